// Round 3
// baseline (36066.919 us; speedup 1.0000x reference)
//
#include <hip/hip_runtime.h>

#define HID 64
#define NF 8
#define IND 14

typedef float f2 __attribute__((ext_vector_type(2)));
typedef float f4 __attribute__((ext_vector_type(4)));
typedef short s8 __attribute__((ext_vector_type(8)));

__device__ __forceinline__ unsigned short f2bf(float x) {
  unsigned u = __float_as_uint(x);
  unsigned r = u + 0x7FFFu + ((u >> 16) & 1u);
  return (unsigned short)(r >> 16);
}
__device__ __forceinline__ float bf2f(unsigned short b) {
  return __uint_as_float(((unsigned)b) << 16);
}

__device__ __forceinline__ float tanh_fast(float x) {
  float ax = fabsf(x);
  float e = __expf(-2.0f * ax);
  float r = __fdividef(1.0f - e, 1.0f + e);
  return x < 0.0f ? -r : r;
}
__device__ __forceinline__ float act_gate(float x, bool is_tanh_lane) {
  float e = __expf(-x);
  float s = __fdividef(1.0f, 1.0f + e);
  float t = tanh_fast(x);
  return is_tanh_lane ? t : s;
}

template <int CTRL>
__device__ __forceinline__ float qp(float x) {
  return __int_as_float(
      __builtin_amdgcn_update_dpp(0, __float_as_int(x), CTRL, 0xF, 0xF, true));
}

__device__ __forceinline__ s8 rdfrag(const unsigned short* hi,
                                     const unsigned short* lo,
                                     int bsel, int kg, int ch) {
  const unsigned short* p = bsel ? lo : hi;
  return *(const s8*)(p + ch * 32 + kg * 8);
}

// One persistent block, 256 threads (4 waves, 1/SIMD).
// The three 256x64 matvecs (Whh0@h0, Whh1@h1, Wih1@h0new) run on MFMA
// (16x16x32 bf16) with weights resident as A-fragments in registers,
// hi/lo bf16 split for both W and h (full 2x2 cross terms -> ~1e-5 error).
// Wave w owns row-tiles 4w..4w+3 (= gate w rows). h crosses waves as 64
// bf16 hi/lo pairs in LDS. Activation keeps R1's quad scheme (lane 4u+k
// owns gate k of unit u; quad_perm DPP exchange; exact fp32 c/h update).
// Head (hiddenfc/outputfc) stays on VALU, pipelined 1-2 steps behind.
__global__ __launch_bounds__(256, 1) void decoder_seq(
    const float* __restrict__ h0in, const float* __restrict__ c0in,
    const float* __restrict__ diffp, const float* __restrict__ target,
    const float* __restrict__ Wih0, const float* __restrict__ Whh0,
    const float* __restrict__ bih0, const float* __restrict__ bhh0,
    const float* __restrict__ Wih1, const float* __restrict__ Whh1,
    const float* __restrict__ bih1, const float* __restrict__ bhh1,
    const float* __restrict__ Whid, const float* __restrict__ bhidp,
    const float* __restrict__ Woutp, const float* __restrict__ boutp,
    float* __restrict__ outp, const int T)
{
  const int tid = threadIdx.x;
  const int w = tid >> 6;
  const int l = tid & 63;
  const int q = l >> 2;
  const int k = l & 3;
  const int u = 16 * w + q;        // hidden unit (act scheme)
  const int r = 64 * k + u;        // gate row (act scheme)
  const bool isg = (k == 2);
  const bool isk0 = (k == 0);
  const int m16 = l & 15;          // MFMA: row-in-tile (A) / col (B,D)
  const int kg = l >> 4;           // MFMA: k-group
  const int bsel = (m16 == 1) ? 1 : 0;

  __shared__ alignas(16) float g0s[256];
  __shared__ alignas(16) float g1s[256];
  __shared__ alignas(16) unsigned short hh0[64], hl0[64], hh1[64], hl1[64];
  __shared__ alignas(16) float h1s[64];
  __shared__ alignas(16) float hidpart[256];
  __shared__ alignas(16) float hidb[32];
  __shared__ alignas(16) float outpart[32];
  __shared__ alignas(16) float obuf[32 * NF];
  __shared__ alignas(16) float tbuf[2 * 32 * NF];

  // ---- A-fragments: [matrix][tile][chunk][hi/lo], 192 VGPRs ----
  s8 fr[3][4][2][2];
  {
    const float* Ws[3] = {Whh0, Whh1, Wih1};
    #pragma unroll
    for (int mm = 0; mm < 3; ++mm)
      #pragma unroll
      for (int tt = 0; tt < 4; ++tt)
        #pragma unroll
        for (int ch = 0; ch < 2; ++ch) {
          const int row = (w * 4 + tt) * 16 + m16;
          const float* src = Ws[mm] + row * HID + ch * 32 + kg * 8;
          f4 pa = *(const f4*)src;
          f4 pb = *(const f4*)(src + 4);
          float vals[8] = {pa.x, pa.y, pa.z, pa.w, pb.x, pb.y, pb.z, pb.w};
          s8 hi8, lo8;
          #pragma unroll
          for (int j = 0; j < 8; ++j) {
            unsigned short hb = f2bf(vals[j]);
            hi8[j] = (short)hb;
            lo8[j] = (short)f2bf(vals[j] - bf2f(hb));
          }
          fr[mm][tt][ch][0] = hi8;
          fr[mm][tt][ch][1] = lo8;
        }
  }

  // ---- x-projection weights (quad-scheme row r) ----
  f2 wxv[4];
  float xc_diff;
  float bias0r, bias1r;
  {
    float wx[IND];
    #pragma unroll
    for (int m = 0; m < IND; ++m) wx[m] = Wih0[r * IND + m];
    wxv[0] = (f2){wx[0], wx[1]}; wxv[1] = (f2){wx[2], wx[3]};
    wxv[2] = (f2){wx[4], wx[5]}; wxv[3] = (f2){wx[6], wx[7]};
    xc_diff = 0.0f;
    #pragma unroll
    for (int m = 0; m < 6; ++m) xc_diff += wx[8 + m] * diffp[m];
    bias0r = bih0[r] + bhh0[r];
    bias1r = bih1[r] + bhh1[r];
  }
  // ---- head weights ----
  f2 whidv[4], woutv[4];
  float bhid_r = 0.0f, bout_r = 0.0f;
  {
    const int j = tid >> 3, seg = tid & 7;
    const f4* ph = (const f4*)&Whid[j * HID + seg * 8];
    f4 ha = ph[0], hb = ph[1];
    whidv[0] = ha.lo; whidv[1] = ha.hi; whidv[2] = hb.lo; whidv[3] = hb.hi;
  }
  if (tid >= 64 && tid < 96) bhid_r = bhidp[tid - 64];
  if (tid >= 96 && tid < 104) bout_r = boutp[tid - 96];
  if (tid >= 192 && tid < 224) {
    const int idx = tid - 192, f = idx >> 2, sg = idx & 3;
    const f4* pw = (const f4*)&Woutp[f * 32 + sg * 8];
    f4 wa = pw[0], wb = pw[1];
    woutv[0] = wa.lo; woutv[1] = wa.hi; woutv[2] = wb.lo; woutv[3] = wb.hi;
  }

  // ---- state init ----
  float c0r = 0.0f, c1r = 0.0f;
  if (isk0) { c0r = c0in[u]; c1r = c0in[64 + u]; }
  if (tid < 64) {
    float v = h0in[tid];
    unsigned short hb = f2bf(v);
    hh0[tid] = hb; hl0[tid] = f2bf(v - bf2f(hb));
  } else if (tid < 128) {
    const int j = tid - 64;
    float v = h0in[64 + j];
    unsigned short hb = f2bf(v);
    hh1[j] = hb; hl1[j] = f2bf(v - bf2f(hb));
    h1s[j] = v;
  }
  if (tid >= 128 && tid < 192) {
    const int lane = tid - 128;
    #pragma unroll
    for (int c = 0; c < 2; ++c) {
      if (c * 32 < T) {
        f4 tv = *(const f4*)&target[c * 256 + lane * 4];
        *(f4*)&tbuf[c * 256 + lane * 4] = tv;
      }
    }
  }
  float xc = 0.0f;
  float h0last = 0.0f, h1last = 0.0f;
  __syncthreads();

  for (int t = 0; t < T; ++t) {
    // ================= PHASE A (pre-B1) =================
    if ((t & 31) == 2 && t >= 34 && w == 2) {
      f4 val = *(const f4*)&obuf[l * 4];
      *(f4*)&outp[(t - 34) * NF + l * 4] = val;
      const int cl = ((t - 2) >> 5) + 1;
      if (cl * 32 < T) {
        f4 tv = *(const f4*)&target[cl * 256 + l * 4];
        *(f4*)&tbuf[(cl & 1) * 256 + l * 4] = tv;
      }
    }
    f4 aB[4];
    {
      s8 b0c0 = rdfrag(hh0, hl0, bsel, kg, 0);
      s8 b0c1 = rdfrag(hh0, hl0, bsel, kg, 1);
      s8 b1c0 = rdfrag(hh1, hl1, bsel, kg, 0);
      s8 b1c1 = rdfrag(hh1, hl1, bsel, kg, 1);
      #pragma unroll
      for (int tt = 0; tt < 4; ++tt) {
        f4 a = {0.f, 0.f, 0.f, 0.f};
        a = __builtin_amdgcn_mfma_f32_16x16x32_bf16(fr[0][tt][0][0], b0c0, a, 0, 0, 0);
        a = __builtin_amdgcn_mfma_f32_16x16x32_bf16(fr[0][tt][0][1], b0c0, a, 0, 0, 0);
        a = __builtin_amdgcn_mfma_f32_16x16x32_bf16(fr[0][tt][1][0], b0c1, a, 0, 0, 0);
        a = __builtin_amdgcn_mfma_f32_16x16x32_bf16(fr[0][tt][1][1], b0c1, a, 0, 0, 0);
        f4 b = {0.f, 0.f, 0.f, 0.f};
        b = __builtin_amdgcn_mfma_f32_16x16x32_bf16(fr[1][tt][0][0], b1c0, b, 0, 0, 0);
        b = __builtin_amdgcn_mfma_f32_16x16x32_bf16(fr[1][tt][0][1], b1c0, b, 0, 0, 0);
        b = __builtin_amdgcn_mfma_f32_16x16x32_bf16(fr[1][tt][1][0], b1c1, b, 0, 0, 0);
        b = __builtin_amdgcn_mfma_f32_16x16x32_bf16(fr[1][tt][1][1], b1c1, b, 0, 0, 0);
        aB[tt] = b;
        // combine col0+col1, store gates0 preact (rows contiguous in regs)
        float v0 = a.x + qp<0xB1>(a.x);
        float v1 = a.y + qp<0xB1>(a.y);
        float v2 = a.z + qp<0xB1>(a.z);
        float v3 = a.w + qp<0xB1>(a.w);
        if (m16 == 0) {
          f4 st = {v0, v1, v2, v3};
          *(f4*)&g0s[(w * 4 + tt) * 16 + kg * 4] = st;
        }
      }
    }
    // head: hidpart(t-1) from h1s, outpart(t-2) from hidb
    {
      const f4* hseg = (const f4*)&h1s[(tid & 7) * 8];
      f4 p = hseg[0], qv = hseg[1];
      f2 hp = whidv[0] * p.lo;
      hp += whidv[1] * p.hi;
      hp += whidv[2] * qv.lo;
      hp += whidv[3] * qv.hi;
      hidpart[tid] = hp.x + hp.y;
    }
    if (tid >= 192 && tid < 224) {
      const int idx = tid - 192, sg = idx & 3;
      const f4* hb4 = (const f4*)&hidb[sg * 8];
      f4 p = hb4[0], qv = hb4[1];
      f2 op = woutv[0] * p.lo;
      op += woutv[1] * p.hi;
      op += woutv[2] * qv.lo;
      op += woutv[3] * qv.hi;
      outpart[idx] = op.x + op.y;
    }
    __syncthreads();  // B1
    // ================= ACT0 =================
    {
      float g = g0s[r] + bias0r + xc;
      float a = act_gate(g, isg);
      float A1 = qp<0xB1>(a), A2 = qp<0x4E>(a), A3 = qp<0x1B>(a);
      if (isk0) {
        c0r = A1 * c0r + a * A2;
        float h = A3 * tanh_fast(c0r);
        h0last = h;
        unsigned short hb = f2bf(h);
        hh0[u] = hb;
        hl0[u] = f2bf(h - bf2f(hb));
      }
    }
    __syncthreads();  // B2
    // ================= PHASE B =================
    {
      s8 bc0 = rdfrag(hh0, hl0, bsel, kg, 0);
      s8 bc1 = rdfrag(hh0, hl0, bsel, kg, 1);
      #pragma unroll
      for (int tt = 0; tt < 4; ++tt) {
        f4 b = aB[tt];
        b = __builtin_amdgcn_mfma_f32_16x16x32_bf16(fr[2][tt][0][0], bc0, b, 0, 0, 0);
        b = __builtin_amdgcn_mfma_f32_16x16x32_bf16(fr[2][tt][0][1], bc0, b, 0, 0, 0);
        b = __builtin_amdgcn_mfma_f32_16x16x32_bf16(fr[2][tt][1][0], bc1, b, 0, 0, 0);
        b = __builtin_amdgcn_mfma_f32_16x16x32_bf16(fr[2][tt][1][1], bc1, b, 0, 0, 0);
        float v0 = b.x + qp<0xB1>(b.x);
        float v1 = b.y + qp<0xB1>(b.y);
        float v2 = b.z + qp<0xB1>(b.z);
        float v3 = b.w + qp<0xB1>(b.w);
        if (m16 == 0) {
          f4 st = {v0, v1, v2, v3};
          *(f4*)&g1s[(w * 4 + tt) * 16 + kg * 4] = st;
        }
      }
      // hidb(t-1)
      if (tid >= 64 && tid < 96) {
        const int j = tid - 64;
        const f4* hp = (const f4*)&hidpart[j * 8];
        f4 p = hp[0], qv = hp[1];
        hidb[j] = bhid_r + (((p.x + p.y) + (p.z + p.w)) +
                            ((qv.x + qv.y) + (qv.z + qv.w)));
      }
      // outfinal(t-2) -> obuf
      if (t >= 2 && tid >= 96 && tid < 104) {
        const int f = tid - 96;
        f4 v = *(const f4*)&outpart[4 * f];
        float s = (v.x + v.y) + (v.z + v.w) + bout_r;
        obuf[((t - 2) & 31) * NF + f] = rintf(s);
      }
    }
    __syncthreads();  // B3
    // ================= ACT1 + x-proj(t+1) =================
    {
      float g = g1s[r] + bias1r;
      float a = act_gate(g, isg);
      float A1 = qp<0xB1>(a), A2 = qp<0x4E>(a), A3 = qp<0x1B>(a);
      if (isk0) {
        c1r = A1 * c1r + a * A2;
        float h = A3 * tanh_fast(c1r);
        h1last = h;
        unsigned short hb = f2bf(h);
        hh1[u] = hb;
        hl1[u] = f2bf(h - bf2f(hb));
        h1s[u] = h;
      }
      const f4* trow = (const f4*)&tbuf[((t >> 5) & 1) * 256 + (t & 31) * 8];
      f4 r0 = trow[0], r1 = trow[1];
      f2 xa = wxv[0] * r0.lo;
      xa += wxv[1] * r0.hi;
      xa += wxv[2] * r1.lo;
      xa += wxv[3] * r1.hi;
      xc = xc_diff + xa.x + xa.y;
    }
    __syncthreads();  // B4
  }

  // ================= EPILOGUE =================
  {
    const f4* hseg = (const f4*)&h1s[(tid & 7) * 8];
    f4 p = hseg[0], qv = hseg[1];
    f2 hp = whidv[0] * p.lo;
    hp += whidv[1] * p.hi;
    hp += whidv[2] * qv.lo;
    hp += whidv[3] * qv.hi;
    hidpart[tid] = hp.x + hp.y;
  }
  if (tid >= 192 && tid < 224) {
    const int idx = tid - 192, sg = idx & 3;
    const f4* hb4 = (const f4*)&hidb[sg * 8];
    f4 p = hb4[0], qv = hb4[1];
    f2 op = woutv[0] * p.lo;
    op += woutv[1] * p.hi;
    op += woutv[2] * qv.lo;
    op += woutv[3] * qv.hi;
    outpart[idx] = op.x + op.y;
  }
  __syncthreads();
  if (tid >= 64 && tid < 96) {
    const int j = tid - 64;
    const f4* hp = (const f4*)&hidpart[j * 8];
    f4 p = hp[0], qv = hp[1];
    hidb[j] = bhid_r + (((p.x + p.y) + (p.z + p.w)) +
                        ((qv.x + qv.y) + (qv.z + qv.w)));
  }
  if (tid >= 96 && tid < 104) {
    const int f = tid - 96;
    f4 v = *(const f4*)&outpart[4 * f];
    float s = (v.x + v.y) + (v.z + v.w) + bout_r;
    obuf[((T - 2) & 31) * NF + f] = rintf(s);
  }
  __syncthreads();
  if (tid >= 192 && tid < 224) {
    const int idx = tid - 192, sg = idx & 3;
    const f4* hb4 = (const f4*)&hidb[sg * 8];
    f4 p = hb4[0], qv = hb4[1];
    f2 op = woutv[0] * p.lo;
    op += woutv[1] * p.hi;
    op += woutv[2] * qv.lo;
    op += woutv[3] * qv.hi;
    outpart[idx] = op.x + op.y;
  }
  __syncthreads();
  if (tid >= 96 && tid < 104) {
    const int f = tid - 96;
    f4 v = *(const f4*)&outpart[4 * f];
    float s = (v.x + v.y) + (v.z + v.w) + bout_r;
    obuf[((T - 1) & 31) * NF + f] = rintf(s);
  }
  if (isk0) {
    const int base = T * NF;
    outp[base + u]        = h0last;
    outp[base + 64 + u]   = h1last;
    outp[base + 128 + u]  = c0r;
    outp[base + 192 + u]  = c1r;
  }
  __syncthreads();
  if (tid >= 128 && tid < 192) {
    const int lane = tid - 128;
    const int tail_start = ((T - 34) / 32) * 32 + 32;
    f4 val = *(const f4*)&obuf[lane * 4];
    *(f4*)&outp[tail_start * NF + lane * 4] = val;
  }
}

extern "C" void kernel_launch(void* const* d_in, const int* in_sizes, int n_in,
                              void* d_out, int out_size, void* d_ws, size_t ws_size,
                              hipStream_t stream) {
  const float* h0in   = (const float*)d_in[1];
  const float* c0in   = (const float*)d_in[2];
  const float* diffp  = (const float*)d_in[3];
  const float* target = (const float*)d_in[4];
  const float* Wih0   = (const float*)d_in[5];
  const float* Whh0   = (const float*)d_in[6];
  const float* bih0   = (const float*)d_in[7];
  const float* bhh0   = (const float*)d_in[8];
  const float* Wih1   = (const float*)d_in[9];
  const float* Whh1   = (const float*)d_in[10];
  const float* bih1   = (const float*)d_in[11];
  const float* bhh1   = (const float*)d_in[12];
  const float* Whid   = (const float*)d_in[13];
  const float* bhidp  = (const float*)d_in[14];
  const float* Woutp  = (const float*)d_in[15];
  const float* boutp  = (const float*)d_in[16];
  float* outp = (float*)d_out;
  const int T = in_sizes[4] / NF;

  decoder_seq<<<dim3(1), dim3(256), 0, stream>>>(
      h0in, c0in, diffp, target,
      Wih0, Whh0, bih0, bhh0,
      Wih1, Whh1, bih1, bhh1,
      Whid, bhidp, Woutp, boutp,
      outp, T);
}

// Round 4
// 14514.455 us; speedup vs baseline: 2.4849x; 2.4849x over previous
//
#include <hip/hip_runtime.h>

#define HID 64
#define NF 8
#define IND 14

typedef float f2 __attribute__((ext_vector_type(2)));
typedef float f4 __attribute__((ext_vector_type(4)));

__device__ __forceinline__ float tanh_fast(float x) {
  float ax = fabsf(x);
  float e = __expf(-2.0f * ax);              // in (0,1]
  float r = __fdividef(1.0f - e, 1.0f + e);
  return x < 0.0f ? -r : r;
}
__device__ __forceinline__ float act_gate(float x, bool is_tanh_lane) {
  float e = __expf(-x);
  float s = __fdividef(1.0f, 1.0f + e);
  float t = tanh_fast(x);
  return is_tanh_lane ? t : s;
}
template <int CTRL>
__device__ __forceinline__ float qp(float x) {
  return __int_as_float(
      __builtin_amdgcn_update_dpp(0, __float_as_int(x), CTRL, 0xF, 0xF, true));
}

// 512 threads = 8 waves, 2/SIMD. Waves 0-3 = "L0 group" (layer-0 LSTM + head
// + IO), waves 4-7 = "L1 group" (layer-1 LSTM). Software pipeline: phase t
// computes h0[t] (L0) and h1[t-1] (L1) concurrently; ONE barrier per phase.
// All cross-wave data in parity-double-buffered LDS. Dots are fp32 VALU with
// lane-pair input-split (even/odd lanes take different halves; one quad_perm
// DPP add combines) -> halves LDS broadcast reads and weight VGPRs.
// Gate preacts stay in registers; activation = quad DPP exchange (lane 4u+k
// holds gate k of unit u; k0 lane updates c,h exactly in fp32).
__global__ __launch_bounds__(512, 2) void decoder_pipe(
    const float* __restrict__ h0in, const float* __restrict__ c0in,
    const float* __restrict__ diffp, const float* __restrict__ target,
    const float* __restrict__ Wih0, const float* __restrict__ Whh0,
    const float* __restrict__ bih0, const float* __restrict__ bhh0,
    const float* __restrict__ Wih1, const float* __restrict__ Whh1,
    const float* __restrict__ bih1, const float* __restrict__ bhh1,
    const float* __restrict__ Whid, const float* __restrict__ bhidp,
    const float* __restrict__ Woutp, const float* __restrict__ boutp,
    float* __restrict__ outp, const int T)
{
  const int tid = threadIdx.x;
  const bool isL1 = tid >= 256;
  const int gl = tid & 255;         // index within group
  const int w  = gl >> 6;           // wave within group
  const int l  = tid & 63;
  const int k  = l & 3;             // gate (i,f,g,o)
  const int u  = 16 * w + (l >> 2); // hidden unit
  const int r  = 64 * k + u;        // own gate row
  const int kp = k & 2;
  const int rA = 64 * kp + u;       // pair's even row
  const int rB = 64 * (kp + 1) + u; // pair's odd row
  const bool odd  = (l & 1);
  const bool isk0 = (k == 0);
  const bool isg  = (k == 2);

  __shared__ alignas(16) float h0ring[2][64];
  __shared__ alignas(16) float h1ring[2][64];
  __shared__ alignas(16) float hidpartS[2][256];
  __shared__ alignas(16) float hidbS[2][32];
  __shared__ alignas(16) float obuf[64 * NF];      // 64-step output ring
  __shared__ alignas(16) float tbuf[2][32 * NF];   // target double buffer

  // ---- weights in registers ----
  f2 wA[32], wB[32];                 // L1: full rows (64 f32); L0: half rows
  float bias_r;
  f2 wxv[4];  float xc_diff = 0.0f;
  f2 whidv[4]; float bhid_r = 0.0f;
  f2 woutv[4]; float bout_r = 0.0f;

  if (isL1) {
    const float* WbA = odd ? (Whh1 + rA * HID) : (Wih1 + rA * HID);
    const float* WbB = odd ? (Whh1 + rB * HID) : (Wih1 + rB * HID);
    #pragma unroll
    for (int kk = 0; kk < 16; ++kk) {
      f4 a = *(const f4*)(WbA + 4 * kk); wA[2*kk] = a.lo; wA[2*kk+1] = a.hi;
      f4 b = *(const f4*)(WbB + 4 * kk); wB[2*kk] = b.lo; wB[2*kk+1] = b.hi;
    }
    bias_r = bih1[r] + bhh1[r];
  } else {
    const int co = odd ? 32 : 0;     // K-half split for layer 0
    const float* WbA = Whh0 + rA * HID + co;
    const float* WbB = Whh0 + rB * HID + co;
    #pragma unroll
    for (int kk = 0; kk < 8; ++kk) {
      f4 a = *(const f4*)(WbA + 4 * kk); wA[2*kk] = a.lo; wA[2*kk+1] = a.hi;
      f4 b = *(const f4*)(WbB + 4 * kk); wB[2*kk] = b.lo; wB[2*kk+1] = b.hi;
    }
    bias_r = bih0[r] + bhh0[r];
    float wx[IND];
    #pragma unroll
    for (int m = 0; m < IND; ++m) wx[m] = Wih0[r * IND + m];
    wxv[0] = (f2){wx[0], wx[1]}; wxv[1] = (f2){wx[2], wx[3]};
    wxv[2] = (f2){wx[4], wx[5]}; wxv[3] = (f2){wx[6], wx[7]};
    xc_diff = 0.0f;
    #pragma unroll
    for (int m = 0; m < 6; ++m) xc_diff += wx[8 + m] * diffp[m];
    // head weights (head runs on L0 group)
    const int j = gl >> 3, seg = gl & 7;
    const f4* ph = (const f4*)&Whid[j * HID + seg * 8];
    f4 ha = ph[0], hb = ph[1];
    whidv[0] = ha.lo; whidv[1] = ha.hi; whidv[2] = hb.lo; whidv[3] = hb.hi;
    if (gl >= 64 && gl < 96) bhid_r = bhidp[gl - 64];
    if (gl >= 160 && gl < 192) {
      const int idx = gl - 160, f = idx >> 2, sg = idx & 3;
      const f4* pw = (const f4*)&Woutp[f * 32 + sg * 8];
      f4 wa = pw[0], wb = pw[1];
      woutv[0] = wa.lo; woutv[1] = wa.hi; woutv[2] = wb.lo; woutv[3] = wb.hi;
      bout_r = boutp[f];
    }
  }

  float cr = 0.0f;
  if (isk0) cr = isL1 ? c0in[64 + u] : c0in[u];

  // ring slot 1 = states at "t = -1"
  if (tid < 64) h0ring[1][tid] = h0in[tid];
  else if (tid < 128) h1ring[1][tid - 64] = h0in[tid];
  if (!isL1 && gl >= 192) {
    const int j = gl - 192;
    #pragma unroll
    for (int c = 0; c < 2; ++c) {
      const int base = c * 256 + j * 4;
      if (base + 3 < T * NF)
        *(f4*)&tbuf[c][j * 4] = *(const f4*)&target[base];
    }
  }
  float xc = 0.0f;   // x(0) = zeros
  __syncthreads();

  const int tend = T + 3;
  for (int t = 0; t <= tend; ++t) {
    const int p = t & 1;
    if (!isL1) {
      // ---- x-projection for phase t+1 (uses target[t]) ----
      float xc_next = 0.0f;
      if (t < T - 1) {
        const f4* trow = (const f4*)&tbuf[(t >> 5) & 1][(t & 31) * NF];
        f4 r0 = trow[0], r1 = trow[1];
        f2 xa = wxv[0] * r0.lo; xa += wxv[1] * r0.hi;
        xa += wxv[2] * r1.lo;  xa += wxv[3] * r1.hi;
        xc_next = xc_diff + xa.x + xa.y;
      }
      // ---- layer 0: h0[t] = cell(x(t), h0[t-1]) ----
      if (t < T) {
        const f4* hb4 = (const f4*)&h0ring[p ^ 1][odd ? 32 : 0];
        f2 sA = {0.f, 0.f}, sB = {0.f, 0.f};
        #pragma unroll
        for (int kk = 0; kk < 8; ++kk) {
          f4 hv = hb4[kk];
          sA += wA[2*kk] * hv.lo; sA += wA[2*kk+1] * hv.hi;
          sB += wB[2*kk] * hv.lo; sB += wB[2*kk+1] * hv.hi;
        }
        float pA = sA.x + sA.y, pB = sB.x + sB.y;
        float SA = pA + qp<0xB1>(pA);     // combine K-halves across lane pair
        float SB = pB + qp<0xB1>(pB);
        float g = (odd ? SB : SA) + bias_r + xc;
        float a = act_gate(g, isg);
        float A1 = qp<0xB1>(a), A2 = qp<0x4E>(a), A3 = qp<0x1B>(a);
        if (isk0) { cr = A1 * cr + a * A2; h0ring[p][u] = A3 * tanh_fast(cr); }
      }
      // ---- head stage 1: hidpart(t-2) from h1[t-2] ----
      if (t >= 2 && t <= T + 1) {
        const f4* hseg = (const f4*)&h1ring[p][(gl & 7) * 8];
        f4 pp = hseg[0], qq = hseg[1];
        f2 hp = whidv[0] * pp.lo; hp += whidv[1] * pp.hi;
        hp += whidv[2] * qq.lo;  hp += whidv[3] * qq.hi;
        hidpartS[p][gl] = hp.x + hp.y;
      }
      // ---- head stage 2: hidb(t-3) ----
      if (t >= 3 && t <= T + 2 && gl >= 64 && gl < 96) {
        const int j = gl - 64;
        const f4* hp4 = (const f4*)&hidpartS[p ^ 1][j * 8];
        f4 pp = hp4[0], qq = hp4[1];
        hidbS[p ^ 1][j] = bhid_r + (((pp.x + pp.y) + (pp.z + pp.w)) +
                                    ((qq.x + qq.y) + (qq.z + qq.w)));
      }
      // ---- head stage 3: out(t-4) via in-wave quad reduce ----
      if (t >= 4 && gl >= 160 && gl < 192) {
        const int idx = gl - 160, sg = idx & 3, f = idx >> 2;
        const f4* hb2 = (const f4*)&hidbS[p][sg * 8];
        f4 pp = hb2[0], qq = hb2[1];
        f2 op = woutv[0] * pp.lo; op += woutv[1] * pp.hi;
        op += woutv[2] * qq.lo;  op += woutv[3] * qq.hi;
        float part = op.x + op.y;
        float v = part + qp<0xB1>(part);
        v = v + qp<0x4E>(v);
        if (sg == 0) obuf[((t - 4) & 63) * NF + f] = rintf(v + bout_r);
      }
      // ---- IO wave: flush outs / prefetch targets ----
      if (gl >= 192) {
        const int j = gl - 192;
        if ((t & 31) == 4 && t >= 36) {
          const int s = (t - 36) + (j >> 1);
          const int off = (j & 1) * 4;
          *(f4*)&outp[s * NF + off] = *(const f4*)&obuf[(s & 63) * NF + off];
        }
        if ((t & 31) == 12) {
          const int cl = (t >> 5) + 1;
          const int base = cl * 256 + j * 4;
          if (base + 3 < T * NF)
            *(f4*)&tbuf[cl & 1][j * 4] = *(const f4*)&target[base];
        }
      }
      xc = xc_next;
    } else {
      // ---- layer 1: h1[t-1] = cell(h0[t-1], h1[t-2]) ----
      if (t >= 1 && t <= T) {
        const f4* hv4 = odd ? (const f4*)h1ring[p] : (const f4*)h0ring[p ^ 1];
        f2 sA = {0.f, 0.f}, sB = {0.f, 0.f};
        #pragma unroll
        for (int kk = 0; kk < 16; ++kk) {
          f4 hv = hv4[kk];
          sA += wA[2*kk] * hv.lo; sA += wA[2*kk+1] * hv.hi;
          sB += wB[2*kk] * hv.lo; sB += wB[2*kk+1] * hv.hi;
        }
        float pA = sA.x + sA.y, pB = sB.x + sB.y;
        float SA = pA + qp<0xB1>(pA);   // even: Wih1@h0 part, odd: Whh1@h1 part
        float SB = pB + qp<0xB1>(pB);
        float g = (odd ? SB : SA) + bias_r;
        float a = act_gate(g, isg);
        float A1 = qp<0xB1>(a), A2 = qp<0x4E>(a), A3 = qp<0x1B>(a);
        if (isk0) { cr = A1 * cr + a * A2; h1ring[p ^ 1][u] = A3 * tanh_fast(cr); }
      }
    }
    __syncthreads();
  }

  // ================= EPILOGUE =================
  // tail outputs not covered by the last in-loop flush
  const int tlast = tend - ((tend - 4) & 31);   // largest t<=tend, t%32==4
  const int s0 = tlast - 4;
  for (int idx = tid; idx < (T - s0) * NF; idx += 512) {
    const int s = s0 + (idx >> 3);
    outp[s * NF + (idx & 7)] = obuf[(s & 63) * NF + (idx & 7)];
  }
  // final states
  const int fs = (T - 1) & 1;
  const int base = T * NF;
  if (tid < 64) outp[base + tid] = h0ring[fs][tid];
  else if (tid < 128) outp[base + 64 + (tid - 64)] = h1ring[fs][tid - 64];
  if (isk0) {
    if (!isL1) outp[base + 128 + u] = cr;
    else       outp[base + 192 + u] = cr;
  }
}

extern "C" void kernel_launch(void* const* d_in, const int* in_sizes, int n_in,
                              void* d_out, int out_size, void* d_ws, size_t ws_size,
                              hipStream_t stream) {
  const float* h0in   = (const float*)d_in[1];
  const float* c0in   = (const float*)d_in[2];
  const float* diffp  = (const float*)d_in[3];
  const float* target = (const float*)d_in[4];
  const float* Wih0   = (const float*)d_in[5];
  const float* Whh0   = (const float*)d_in[6];
  const float* bih0   = (const float*)d_in[7];
  const float* bhh0   = (const float*)d_in[8];
  const float* Wih1   = (const float*)d_in[9];
  const float* Whh1   = (const float*)d_in[10];
  const float* bih1   = (const float*)d_in[11];
  const float* bhh1   = (const float*)d_in[12];
  const float* Whid   = (const float*)d_in[13];
  const float* bhidp  = (const float*)d_in[14];
  const float* Woutp  = (const float*)d_in[15];
  const float* boutp  = (const float*)d_in[16];
  float* outp = (float*)d_out;
  const int T = in_sizes[4] / NF;

  decoder_pipe<<<dim3(1), dim3(512), 0, stream>>>(
      h0in, c0in, diffp, target,
      Wih0, Whh0, bih0, bhh0,
      Wih1, Whh1, bih1, bhh1,
      Whid, bhidp, Woutp, boutp,
      outp, T);
}